// Round 3
// baseline (877.880 us; speedup 1.0000x reference)
//
#include <hip/hip_runtime.h>

#define NLOC 12
#define F_DIM 512
#define H_DIM 256

typedef float f4 __attribute__((ext_vector_type(4)));
typedef _Float16 half4 __attribute__((ext_vector_type(4)));
typedef _Float16 half8 __attribute__((ext_vector_type(8)));

// workspace layout (bytes) — Acat/base eliminated (fused kernel)
#define OFF_W1   0ul
#define OFF_W2   (OFF_W1 + 512ul*512*2)          // W1: [512][512] f16
#define OFF_C1   (OFF_W2 + 512ul*1024*2)         // W2: [512][1024] f16
#define OFF_CVEC (OFF_C1 + 2048ul)               // c1: [512] f32
                                                 // cvec: [512] f32

// ---------------------------------------------------------------------------
// Precompute W1[f,f'] = sum_h Wk[f,h] Wq[f',h]   (mode 0)
//            W2[f,j]  = sum_h Wf[h,f] Wv[j,h]            (mode 1, cols 0..511)
//            W2[f,512+j] = S * sum_h Wf[256+h,f] Wv[j,h] (mode 2)
// mode 3 (2 active blocks): c1 / cvec vectors.
// ---------------------------------------------------------------------------
__global__ void __launch_bounds__(256) precompute_w(
    const float* __restrict__ Wq, const float* __restrict__ Wk,
    const float* __restrict__ Wv, const float* __restrict__ Wf,
    const float* __restrict__ wdr, const float* __restrict__ bq,
    const float* __restrict__ bv, const float* __restrict__ bdr,
    const float* __restrict__ bfv,
    _Float16* __restrict__ W1, _Float16* __restrict__ W2,
    float* __restrict__ c1, float* __restrict__ cvec)
{
    const int mode = blockIdx.z;
    const int t = threadIdx.x;

    if (mode == 3) {
        if (blockIdx.y != 0 || blockIdx.x >= 2) return;
        const int f = blockIdx.x * 256 + t;   // 0..511
        f4 a = {0.f, 0.f, 0.f, 0.f};
        const f4* wk4 = (const f4*)(Wk + (long)f * H_DIM);
        const f4* bq4 = (const f4*)bq;
#pragma unroll 4
        for (int h4 = 0; h4 < H_DIM / 4; ++h4) a += wk4[h4] * bq4[h4];
        c1[f] = a[0] + a[1] + a[2] + a[3];

        float s1 = 0.f, s2 = 0.f, s3 = 0.f;
#pragma unroll 4
        for (int h = 0; h < H_DIM; ++h) {
            float w1v = Wf[h * F_DIM + f];
            float w2v = Wf[(H_DIM + h) * F_DIM + f];
            float bvh = bv[h];
            s1 += bvh * w1v; s2 += bvh * w2v; s3 += w2v;
        }
        float S = 0.f;
#pragma unroll
        for (int k = 0; k < NLOC; ++k) S += wdr[k];
        cvec[f] = s1 + S * s2 + bdr[0] * s3 + bfv[f];
        return;
    }

    __shared__ float X[32][264];
    __shared__ float Y[32][264];
    const int f0 = blockIdx.x * 32;
    const int j0 = blockIdx.y * 32;

    {
        const int r = t >> 3, cb = (t & 7) * 32;
        const float* ysrc = ((mode == 0) ? Wq : Wv) + (j0 + r) * H_DIM + cb;
#pragma unroll
        for (int u = 0; u < 32; u += 4)
            *(f4*)&Y[r][cb + u] = *(const f4*)(ysrc + u);
        if (mode == 0) {
            const float* xsrc = Wk + (f0 + r) * H_DIM + cb;
#pragma unroll
            for (int u = 0; u < 32; u += 4)
                *(f4*)&X[r][cb + u] = *(const f4*)(xsrc + u);
        }
    }
    if (mode != 0) {
        const int h = t;                       // 0..255
        const int hoff = (mode == 2) ? H_DIM : 0;
        const float* xsrc = Wf + (long)(h + hoff) * F_DIM + f0;
        f4 v[8];
#pragma unroll
        for (int u = 0; u < 8; ++u) v[u] = *(const f4*)(xsrc + u * 4);
#pragma unroll
        for (int r = 0; r < 32; ++r) X[r][h] = v[r >> 2][r & 3];
    }
    __syncthreads();

    const int fy = t >> 4, jx = t & 15;
    float a00 = 0.f, a01 = 0.f, a10 = 0.f, a11 = 0.f;
#pragma unroll 8
    for (int h = 0; h < H_DIM; ++h) {
        float x0 = X[fy][h], x1 = X[fy + 16][h];
        float y0 = Y[jx][h], y1 = Y[jx + 16][h];
        a00 += x0 * y0; a01 += x0 * y1; a10 += x1 * y0; a11 += x1 * y1;
    }
    if (mode == 2) {
        float S = 0.f;
#pragma unroll
        for (int k = 0; k < NLOC; ++k) S += wdr[k];
        a00 *= S; a01 *= S; a10 *= S; a11 *= S;
    }
    if (mode == 0) {
        W1[(f0 + fy) * F_DIM + (j0 + jx)]             = (_Float16)a00;
        W1[(f0 + fy) * F_DIM + (j0 + jx + 16)]        = (_Float16)a01;
        W1[(f0 + fy + 16) * F_DIM + (j0 + jx)]        = (_Float16)a10;
        W1[(f0 + fy + 16) * F_DIM + (j0 + jx + 16)]   = (_Float16)a11;
    } else {
        const long co = (mode == 2) ? F_DIM : 0;
        W2[(long)(f0 + fy) * 1024 + co + (j0 + jx)]           = (_Float16)a00;
        W2[(long)(f0 + fy) * 1024 + co + (j0 + jx + 16)]      = (_Float16)a01;
        W2[(long)(f0 + fy + 16) * 1024 + co + (j0 + jx)]      = (_Float16)a10;
        W2[(long)(f0 + fy + 16) * 1024 + co + (j0 + jx + 16)] = (_Float16)a11;
    }
}

// ---------------------------------------------------------------------------
// K1 (fused everything): per 32-row block —
//  stage G (g->f16) -> phase1 T = g@W1^T + c1 (MFMA, barrier-free)
//  -> phase2 local pass (pooled written IN PLACE into T; base stashed in regs)
//  -> phase3 out = relu([T|G] @ W2^T + cvec) + base (MFMA, barrier-free k-loop)
// No Acat/base globals; W1/W2 B-fragments direct from L2.
// LDS: G[32][520] + T[32][520] = 66.5 KB -> 2 blocks/CU; phase-3 (L2-bound)
// of one block overlaps phase-2 (HBM-bound) of the co-resident block.
// ---------------------------------------------------------------------------
__global__ void __launch_bounds__(256, 2) fused_all(
    const float* __restrict__ g, const float* __restrict__ loc,
    const _Float16* __restrict__ W1, const _Float16* __restrict__ W2,
    const float* __restrict__ c1, const float* __restrict__ cvec,
    const float* __restrict__ wdr, const float* __restrict__ bdr,
    float* __restrict__ out)
{
    __shared__ _Float16 G[32][520];
    __shared__ _Float16 T[32][520];
    const int tid = threadIdx.x;
    const int lane = tid & 63;
    const int wave = tid >> 6;
    const int quad = lane >> 4;
    const int l16 = lane & 15;
    const long m0 = (long)blockIdx.x * 32;

    // ---- stage G (f32 -> f16), coalesced
    {
        const int r = tid >> 3;          // 0..31
        const int cb = (tid & 7) * 8;
#pragma unroll
        for (int u = 0; u < 512; u += 64) {
            const float* src = g + (m0 + r) * F_DIM + cb + u;
            f4 v0 = *(const f4*)(src);
            f4 v1 = *(const f4*)(src + 4);
            half8 hv;
#pragma unroll
            for (int j = 0; j < 4; ++j) { hv[j] = (_Float16)v0[j]; hv[4 + j] = (_Float16)v1[j]; }
            *(half8*)&G[r][cb + u] = hv;
        }
    }
    __syncthreads();

    // ---- phase 1: T = G @ W1^T + c1 (barrier-free k-loop, B direct from L2)
    const int wn1 = wave * 32;
    for (int nt = 0; nt < 4; ++nt) {
        const int n0 = nt * 128;
        const _Float16* wb0 = W1 + (long)(n0 + wn1 + l16) * F_DIM + quad * 8;
        const _Float16* wb1 = wb0 + 16 * F_DIM;
        f4 acc[2][2] = {{{0.f,0.f,0.f,0.f},{0.f,0.f,0.f,0.f}},
                        {{0.f,0.f,0.f,0.f},{0.f,0.f,0.f,0.f}}};
#pragma unroll
        for (int k0 = 0; k0 < 512; k0 += 32) {
            half8 b0 = *(const half8*)(wb0 + k0);
            half8 b1 = *(const half8*)(wb1 + k0);
            half8 a0 = *(const half8*)&G[l16][k0 + quad * 8];
            half8 a1 = *(const half8*)&G[16 + l16][k0 + quad * 8];
            acc[0][0] = __builtin_amdgcn_mfma_f32_16x16x32_f16(a0, b0, acc[0][0], 0, 0, 0);
            acc[0][1] = __builtin_amdgcn_mfma_f32_16x16x32_f16(a0, b1, acc[0][1], 0, 0, 0);
            acc[1][0] = __builtin_amdgcn_mfma_f32_16x16x32_f16(a1, b0, acc[1][0], 0, 0, 0);
            acc[1][1] = __builtin_amdgcn_mfma_f32_16x16x32_f16(a1, b1, acc[1][1], 0, 0, 0);
        }
#pragma unroll
        for (int ni = 0; ni < 2; ++ni) {
            const int col = n0 + wn1 + ni * 16 + l16;
            const float cv = c1[col];
#pragma unroll
            for (int mi = 0; mi < 2; ++mi)
#pragma unroll
                for (int i = 0; i < 4; ++i)
                    T[mi * 16 + quad * 4 + i][col] = (_Float16)(acc[mi][ni][i] + cv);
        }
    }

    // ---- phase 2: local pass, 8 rows per wave, half-row pipelined.
    // Pooled result overwrites T[bl] in place; base (lfm+g) stashed in regs.
    const int c0 = lane * 4;
    const int c1i = 256 + lane * 4;
    const float bd = bdr[0];
    float wv[NLOC];
#pragma unroll
    for (int k = 0; k < NLOC; ++k) wv[k] = wdr[k];

    half4 bhA[8], bhB[8];          // base stash: 8 rows x (2 x half4) = 32 VGPR

    f4 laA[NLOC], laB[NLOC];
    {
        const float* lb0 = loc + (m0 + wave * 8) * (NLOC * F_DIM);
#pragma unroll
        for (int k = 0; k < NLOC; ++k) laA[k] = *(const f4*)(lb0 + k * F_DIM + c0);
    }
    __syncthreads();   // T ready (cross-wave); row-0 la loads drain here too

    auto row_body = [&](int rr, f4 (&la)[NLOC], f4 (&laN)[NLOC]) {
        const int bl = wave * 8 + rr;
        const long b = m0 + bl;
        const float* lb = loc + b * (NLOC * F_DIM);

        f4 lbv[NLOC];
#pragma unroll
        for (int k = 0; k < NLOC; ++k)
            lbv[k] = *(const f4*)(lb + k * F_DIM + c1i);
        if (rr < 7) {
            const float* lbn = lb + NLOC * F_DIM;
#pragma unroll
            for (int k = 0; k < NLOC; ++k)
                laN[k] = *(const f4*)(lbn + k * F_DIM + c0);
        }

        f4 taf = __builtin_convertvector(*(const half4*)&T[bl][c0], f4);
        f4 tbf = __builtin_convertvector(*(const half4*)&T[bl][c1i], f4);

        float p[NLOC];
#pragma unroll
        for (int k = 0; k < NLOC; ++k) {
            f4 prod = la[k] * taf + lbv[k] * tbf;
            p[k] = prod[0] + prod[1] + prod[2] + prod[3];
        }
#pragma unroll
        for (int k = 0; k < NLOC; ++k) {
            float v = p[k];
            v += __shfl_xor(v, 1);
            v += __shfl_xor(v, 2);
            v += __shfl_xor(v, 4);
            v += __shfl_xor(v, 8);
            v += __shfl_xor(v, 16);
            v += __shfl_xor(v, 32);
            p[k] = v * 0.0625f;   // scale = 1/sqrt(256)
        }
        float mx = p[0];
#pragma unroll
        for (int k = 1; k < NLOC; ++k) mx = fmaxf(mx, p[k]);
        float e[NLOC], s = 0.f;
#pragma unroll
        for (int k = 0; k < NLOC; ++k) { e[k] = expf(p[k] - mx); s += e[k]; }
        const float inv = 1.f / s;

        f4 pA = {0.f,0.f,0.f,0.f}, pB = {0.f,0.f,0.f,0.f};
        f4 fA = {0.f,0.f,0.f,0.f}, fB = {0.f,0.f,0.f,0.f};
#pragma unroll
        for (int k = 0; k < NLOC; ++k) {
            const float ak = e[k] * inv;
            const float wk = wv[k];
            pA += ak * la[k]; pB += ak * lbv[k];
            fA += wk * la[k]; fB += wk * lbv[k];
        }
        half4 gA = *(const half4*)&G[bl][c0];
        half4 gB = *(const half4*)&G[bl][c1i];
        fA += bd + __builtin_convertvector(gA, f4);
        fB += bd + __builtin_convertvector(gB, f4);

        // pooled -> T in place (taf/tbf already read); base -> reg stash
        *(half4*)&T[bl][c0]  = __builtin_convertvector(pA, half4);
        *(half4*)&T[bl][c1i] = __builtin_convertvector(pB, half4);
        bhA[rr] = __builtin_convertvector(fA, half4);
        bhB[rr] = __builtin_convertvector(fB, half4);
    };

#pragma unroll
    for (int it = 0; it < 4; ++it) {
        row_body(it * 2,     laA, laB);
        row_body(it * 2 + 1, laB, laA);
    }
    __syncthreads();   // pooled (T) visible to all waves

    // ---- phase 3: out = relu([T|G] @ W2^T + cvec) + base.
    // Wave owns 128 output cols; B direct from L2 (W2 read once per block).
    const int wn = wave * 128;
    f4 acc[2][8];
#pragma unroll
    for (int mi = 0; mi < 2; ++mi)
#pragma unroll
        for (int nj = 0; nj < 8; ++nj) acc[mi][nj] = (f4){0.f,0.f,0.f,0.f};

    const _Float16* w2w = W2 + (long)(wn + l16) * 1024 + quad * 8;

    // K-half 1: A from T (pooled), W2 k in [0,512)
#pragma unroll 4
    for (int kt = 0; kt < 16; ++kt) {
        const int k0 = kt * 32;
        half8 a0 = *(const half8*)&T[l16][k0 + quad * 8];
        half8 a1 = *(const half8*)&T[16 + l16][k0 + quad * 8];
#pragma unroll
        for (int nj = 0; nj < 8; ++nj) {
            half8 b = *(const half8*)(w2w + nj * 16 * 1024 + k0);
            acc[0][nj] = __builtin_amdgcn_mfma_f32_16x16x32_f16(a0, b, acc[0][nj], 0, 0, 0);
            acc[1][nj] = __builtin_amdgcn_mfma_f32_16x16x32_f16(a1, b, acc[1][nj], 0, 0, 0);
        }
    }
    // K-half 2: A from G (g), W2 k in [512,1024)
#pragma unroll 4
    for (int kt = 0; kt < 16; ++kt) {
        const int k0 = kt * 32;
        half8 a0 = *(const half8*)&G[l16][k0 + quad * 8];
        half8 a1 = *(const half8*)&G[16 + l16][k0 + quad * 8];
#pragma unroll
        for (int nj = 0; nj < 8; ++nj) {
            half8 b = *(const half8*)(w2w + nj * 16 * 1024 + 512 + k0);
            acc[0][nj] = __builtin_amdgcn_mfma_f32_16x16x32_f16(a0, b, acc[0][nj], 0, 0, 0);
            acc[1][nj] = __builtin_amdgcn_mfma_f32_16x16x32_f16(a1, b, acc[1][nj], 0, 0, 0);
        }
    }

    __syncthreads();   // all waves done reading T (pooled)
    // base stash -> T (now free) for the epilogue transpose
#pragma unroll
    for (int rr = 0; rr < 8; ++rr) {
        const int bl = wave * 8 + rr;
        *(half4*)&T[bl][c0]  = bhA[rr];
        *(half4*)&T[bl][c1i] = bhB[rr];
    }
    __syncthreads();   // base visible to all waves

    // ---- epilogue
#pragma unroll
    for (int nj = 0; nj < 8; ++nj) {
        const int col = wn + nj * 16 + l16;
        const float cv = cvec[col];
#pragma unroll
        for (int mi = 0; mi < 2; ++mi)
#pragma unroll
            for (int i = 0; i < 4; ++i) {
                const int rl = mi * 16 + quad * 4 + i;
                float v = fmaxf(acc[mi][nj][i] + cv, 0.f) + (float)T[rl][col];
                out[(m0 + rl) * F_DIM + col] = v;
            }
    }
}

// ---------------------------------------------------------------------------
extern "C" void kernel_launch(void* const* d_in, const int* in_sizes, int n_in,
                              void* d_out, int out_size, void* d_ws, size_t ws_size,
                              hipStream_t stream)
{
    (void)in_sizes; (void)n_in; (void)out_size; (void)ws_size;
    const float* gf  = (const float*)d_in[0];
    const float* loc = (const float*)d_in[1];
    const float* Wq  = (const float*)d_in[2];
    const float* bq  = (const float*)d_in[3];
    const float* Wk  = (const float*)d_in[4];
    // d_in[5] = bk: dropped — contributes only a k-constant to s2 (softmax-invariant)
    const float* Wv  = (const float*)d_in[6];
    const float* bv  = (const float*)d_in[7];
    const float* wdr = (const float*)d_in[8];
    const float* bdr = (const float*)d_in[9];
    const float* Wf  = (const float*)d_in[10];
    const float* bfv = (const float*)d_in[11];
    float* out = (float*)d_out;

    char* ws = (char*)d_ws;
    _Float16* W1   = (_Float16*)(ws + OFF_W1);
    _Float16* W2   = (_Float16*)(ws + OFF_W2);
    float*    c1   = (float*)(ws + OFF_C1);
    float*    cvec = (float*)(ws + OFF_CVEC);

    precompute_w<<<dim3(16, 16, 4), 256, 0, stream>>>(
        Wq, Wk, Wv, Wf, wdr, bq, bv, bdr, bfv, W1, W2, c1, cvec);
    fused_all<<<512, 256, 0, stream>>>(
        gf, loc, W1, W2, c1, cvec, wdr, bdr, out);
}

// Round 4
// 691.971 us; speedup vs baseline: 1.2687x; 1.2687x over previous
//
#include <hip/hip_runtime.h>

#define NLOC 12
#define F_DIM 512
#define H_DIM 256

typedef float f4 __attribute__((ext_vector_type(4)));
typedef _Float16 half4 __attribute__((ext_vector_type(4)));
typedef _Float16 half8 __attribute__((ext_vector_type(8)));

// workspace layout (bytes)
#define OFF_W1   0ul
#define OFF_W2   (OFF_W1 + 512ul*512*2)          // W1: [512][512] f16
#define OFF_C1   (OFF_W2 + 512ul*1024*2)         // W2: [512][1024] f16
#define OFF_CVEC (OFF_C1 + 2048ul)               // c1: [512] f32
#define OFF_BASE (OFF_CVEC + 2048ul)             // cvec: [512] f32
// base: [B][512] f16  (lfm + g)

// ---------------------------------------------------------------------------
// Precompute W1[f,f'] = sum_h Wk[f,h] Wq[f',h]   (mode 0)
//            W2[f,j]  = sum_h Wf[h,f] Wv[j,h]            (mode 1, cols 0..511)
//            W2[f,512+j] = S * sum_h Wf[256+h,f] Wv[j,h] (mode 2)
// mode 3 (2 active blocks): c1 / cvec vectors.
// ---------------------------------------------------------------------------
__global__ void __launch_bounds__(256) precompute_w(
    const float* __restrict__ Wq, const float* __restrict__ Wk,
    const float* __restrict__ Wv, const float* __restrict__ Wf,
    const float* __restrict__ wdr, const float* __restrict__ bq,
    const float* __restrict__ bv, const float* __restrict__ bdr,
    const float* __restrict__ bfv,
    _Float16* __restrict__ W1, _Float16* __restrict__ W2,
    float* __restrict__ c1, float* __restrict__ cvec)
{
    const int mode = blockIdx.z;
    const int t = threadIdx.x;

    if (mode == 3) {
        if (blockIdx.y != 0 || blockIdx.x >= 2) return;
        const int f = blockIdx.x * 256 + t;   // 0..511
        f4 a = {0.f, 0.f, 0.f, 0.f};
        const f4* wk4 = (const f4*)(Wk + (long)f * H_DIM);
        const f4* bq4 = (const f4*)bq;
#pragma unroll 4
        for (int h4 = 0; h4 < H_DIM / 4; ++h4) a += wk4[h4] * bq4[h4];
        c1[f] = a[0] + a[1] + a[2] + a[3];

        float s1 = 0.f, s2 = 0.f, s3 = 0.f;
#pragma unroll 4
        for (int h = 0; h < H_DIM; ++h) {
            float w1v = Wf[h * F_DIM + f];
            float w2v = Wf[(H_DIM + h) * F_DIM + f];
            float bvh = bv[h];
            s1 += bvh * w1v; s2 += bvh * w2v; s3 += w2v;
        }
        float S = 0.f;
#pragma unroll
        for (int k = 0; k < NLOC; ++k) S += wdr[k];
        cvec[f] = s1 + S * s2 + bdr[0] * s3 + bfv[f];
        return;
    }

    __shared__ float X[32][264];
    __shared__ float Y[32][264];
    const int f0 = blockIdx.x * 32;
    const int j0 = blockIdx.y * 32;

    {
        const int r = t >> 3, cb = (t & 7) * 32;
        const float* ysrc = ((mode == 0) ? Wq : Wv) + (j0 + r) * H_DIM + cb;
#pragma unroll
        for (int u = 0; u < 32; u += 4)
            *(f4*)&Y[r][cb + u] = *(const f4*)(ysrc + u);
        if (mode == 0) {
            const float* xsrc = Wk + (f0 + r) * H_DIM + cb;
#pragma unroll
            for (int u = 0; u < 32; u += 4)
                *(f4*)&X[r][cb + u] = *(const f4*)(xsrc + u);
        }
    }
    if (mode != 0) {
        const int h = t;                       // 0..255
        const int hoff = (mode == 2) ? H_DIM : 0;
        const float* xsrc = Wf + (long)(h + hoff) * F_DIM + f0;
        f4 v[8];
#pragma unroll
        for (int u = 0; u < 8; ++u) v[u] = *(const f4*)(xsrc + u * 4);
#pragma unroll
        for (int r = 0; r < 32; ++r) X[r][h] = v[r >> 2][r & 3];
    }
    __syncthreads();

    const int fy = t >> 4, jx = t & 15;
    float a00 = 0.f, a01 = 0.f, a10 = 0.f, a11 = 0.f;
#pragma unroll 8
    for (int h = 0; h < H_DIM; ++h) {
        float x0 = X[fy][h], x1 = X[fy + 16][h];
        float y0 = Y[jx][h], y1 = Y[jx + 16][h];
        a00 += x0 * y0; a01 += x0 * y1; a10 += x1 * y0; a11 += x1 * y1;
    }
    if (mode == 2) {
        float S = 0.f;
#pragma unroll
        for (int k = 0; k < NLOC; ++k) S += wdr[k];
        a00 *= S; a01 *= S; a10 *= S; a11 *= S;
    }
    if (mode == 0) {
        W1[(f0 + fy) * F_DIM + (j0 + jx)]             = (_Float16)a00;
        W1[(f0 + fy) * F_DIM + (j0 + jx + 16)]        = (_Float16)a01;
        W1[(f0 + fy + 16) * F_DIM + (j0 + jx)]        = (_Float16)a10;
        W1[(f0 + fy + 16) * F_DIM + (j0 + jx + 16)]   = (_Float16)a11;
    } else {
        const long co = (mode == 2) ? F_DIM : 0;
        W2[(long)(f0 + fy) * 1024 + co + (j0 + jx)]           = (_Float16)a00;
        W2[(long)(f0 + fy) * 1024 + co + (j0 + jx + 16)]      = (_Float16)a01;
        W2[(long)(f0 + fy + 16) * 1024 + co + (j0 + jx)]      = (_Float16)a10;
        W2[(long)(f0 + fy + 16) * 1024 + co + (j0 + jx + 16)] = (_Float16)a11;
    }
}

// ---------------------------------------------------------------------------
// K1 (fused, spill-free v2): per 32-row block —
//  stage G (g->f16) -> phase1 T = g@W1^T + c1 (MFMA, barrier-free)
//  -> phase2 local pass (PLAIN #pragma unroll 1 row loop — no lambda, no
//     rotating prefetch arrays; R3's version fully unrolled 8 row bodies,
//     hoisted ~190 f4 loads, spilled ~100 VGPR -> 365 MB scratch writes)
//     pooled written IN PLACE into T; base (lfm+g) -> small global buffer
//  -> phase3 out = relu([T|G] @ W2^T + cvec) + base (MFMA, barrier-free)
// LDS: G[32][520] + T[32][520] = 66.5 KB -> 2 blocks/CU.
// ---------------------------------------------------------------------------
__global__ void __launch_bounds__(256, 2) fused_all(
    const float* __restrict__ g, const float* __restrict__ loc,
    const _Float16* __restrict__ W1, const _Float16* __restrict__ W2,
    const float* __restrict__ c1, const float* __restrict__ cvec,
    const float* __restrict__ wdr, const float* __restrict__ bdr,
    _Float16* __restrict__ base, float* __restrict__ out)
{
    __shared__ _Float16 G[32][520];
    __shared__ _Float16 T[32][520];
    const int tid = threadIdx.x;
    const int lane = tid & 63;
    const int wave = tid >> 6;
    const int quad = lane >> 4;
    const int l16 = lane & 15;
    const long m0 = (long)blockIdx.x * 32;

    // ---- stage G (f32 -> f16), coalesced
    {
        const int r = tid >> 3;          // 0..31
        const int cb = (tid & 7) * 8;
#pragma unroll
        for (int u = 0; u < 512; u += 64) {
            const float* src = g + (m0 + r) * F_DIM + cb + u;
            f4 v0 = *(const f4*)(src);
            f4 v1 = *(const f4*)(src + 4);
            half8 hv;
#pragma unroll
            for (int j = 0; j < 4; ++j) { hv[j] = (_Float16)v0[j]; hv[4 + j] = (_Float16)v1[j]; }
            *(half8*)&G[r][cb + u] = hv;
        }
    }
    __syncthreads();

    // ---- phase 1: T = G @ W1^T + c1 (barrier-free k-loop, B direct from L2)
    const int wn1 = wave * 32;
    for (int nt = 0; nt < 4; ++nt) {
        const int n0 = nt * 128;
        const _Float16* wb0 = W1 + (long)(n0 + wn1 + l16) * F_DIM + quad * 8;
        const _Float16* wb1 = wb0 + 16 * F_DIM;
        f4 acc[2][2] = {{{0.f,0.f,0.f,0.f},{0.f,0.f,0.f,0.f}},
                        {{0.f,0.f,0.f,0.f},{0.f,0.f,0.f,0.f}}};
#pragma unroll
        for (int k0 = 0; k0 < 512; k0 += 32) {
            half8 b0 = *(const half8*)(wb0 + k0);
            half8 b1 = *(const half8*)(wb1 + k0);
            half8 a0 = *(const half8*)&G[l16][k0 + quad * 8];
            half8 a1 = *(const half8*)&G[16 + l16][k0 + quad * 8];
            acc[0][0] = __builtin_amdgcn_mfma_f32_16x16x32_f16(a0, b0, acc[0][0], 0, 0, 0);
            acc[0][1] = __builtin_amdgcn_mfma_f32_16x16x32_f16(a0, b1, acc[0][1], 0, 0, 0);
            acc[1][0] = __builtin_amdgcn_mfma_f32_16x16x32_f16(a1, b0, acc[1][0], 0, 0, 0);
            acc[1][1] = __builtin_amdgcn_mfma_f32_16x16x32_f16(a1, b1, acc[1][1], 0, 0, 0);
        }
#pragma unroll
        for (int ni = 0; ni < 2; ++ni) {
            const int col = n0 + wn1 + ni * 16 + l16;
            const float cv = c1[col];
#pragma unroll
            for (int mi = 0; mi < 2; ++mi)
#pragma unroll
                for (int i = 0; i < 4; ++i)
                    T[mi * 16 + quad * 4 + i][col] = (_Float16)(acc[mi][ni][i] + cv);
        }
    }

    // ---- phase 2: local pass, 8 rows per wave. Plain rolled loop: live set
    // stays ~170 VGPR; latency hidden by 8 waves/CU on a BW-bound stream.
    const int c0 = lane * 4;
    const int c1i = 256 + lane * 4;
    const float bd = bdr[0];
    float wv[NLOC];
#pragma unroll
    for (int k = 0; k < NLOC; ++k) wv[k] = wdr[k];

    __syncthreads();   // T ready (cross-wave)

#pragma unroll 1
    for (int rr = 0; rr < 8; ++rr) {
        const int bl = wave * 8 + rr;
        const long b = m0 + bl;
        const float* lb = loc + b * (NLOC * F_DIM);

        f4 la[NLOC], lbv[NLOC];
#pragma unroll
        for (int k = 0; k < NLOC; ++k) {
            la[k]  = *(const f4*)(lb + k * F_DIM + c0);
            lbv[k] = *(const f4*)(lb + k * F_DIM + c1i);
        }

        f4 taf = __builtin_convertvector(*(const half4*)&T[bl][c0], f4);
        f4 tbf = __builtin_convertvector(*(const half4*)&T[bl][c1i], f4);

        float p[NLOC];
#pragma unroll
        for (int k = 0; k < NLOC; ++k) {
            f4 prod = la[k] * taf + lbv[k] * tbf;
            p[k] = prod[0] + prod[1] + prod[2] + prod[3];
        }
#pragma unroll
        for (int k = 0; k < NLOC; ++k) {
            float v = p[k];
            v += __shfl_xor(v, 1);
            v += __shfl_xor(v, 2);
            v += __shfl_xor(v, 4);
            v += __shfl_xor(v, 8);
            v += __shfl_xor(v, 16);
            v += __shfl_xor(v, 32);
            p[k] = v * 0.0625f;   // scale = 1/sqrt(256)
        }
        float mx = p[0];
#pragma unroll
        for (int k = 1; k < NLOC; ++k) mx = fmaxf(mx, p[k]);
        float e[NLOC], s = 0.f;
#pragma unroll
        for (int k = 0; k < NLOC; ++k) { e[k] = expf(p[k] - mx); s += e[k]; }
        const float inv = 1.f / s;

        f4 pA = {0.f,0.f,0.f,0.f}, pB = {0.f,0.f,0.f,0.f};
        f4 fA = {0.f,0.f,0.f,0.f}, fB = {0.f,0.f,0.f,0.f};
#pragma unroll
        for (int k = 0; k < NLOC; ++k) {
            const float ak = e[k] * inv;
            const float wk = wv[k];
            pA += ak * la[k]; pB += ak * lbv[k];
            fA += wk * la[k]; fB += wk * lbv[k];
        }
        half4 gA = *(const half4*)&G[bl][c0];
        half4 gB = *(const half4*)&G[bl][c1i];
        fA += bd + __builtin_convertvector(gA, f4);
        fB += bd + __builtin_convertvector(gB, f4);

        // pooled -> T in place (own wave's rows; taf/tbf already consumed)
        *(half4*)&T[bl][c0]  = __builtin_convertvector(pA, half4);
        *(half4*)&T[bl][c1i] = __builtin_convertvector(pB, half4);
        // base -> global (L3-hot by the epilogue)
        *(half4*)(base + b * F_DIM + c0)  = __builtin_convertvector(fA, half4);
        *(half4*)(base + b * F_DIM + c1i) = __builtin_convertvector(fB, half4);
    }
    __syncthreads();   // pooled (T) visible to all waves

    // ---- phase 3: out = relu([T|G] @ W2^T + cvec) + base.
    // Wave owns 128 output cols; B direct from L2 (W2 read once per block).
    const int wn = wave * 128;
    f4 acc[2][8];
#pragma unroll
    for (int mi = 0; mi < 2; ++mi)
#pragma unroll
        for (int nj = 0; nj < 8; ++nj) acc[mi][nj] = (f4){0.f,0.f,0.f,0.f};

    const _Float16* w2w = W2 + (long)(wn + l16) * 1024 + quad * 8;

    // K-half 1: A from T (pooled), W2 k in [0,512)
#pragma unroll 4
    for (int kt = 0; kt < 16; ++kt) {
        const int k0 = kt * 32;
        half8 a0 = *(const half8*)&T[l16][k0 + quad * 8];
        half8 a1 = *(const half8*)&T[16 + l16][k0 + quad * 8];
#pragma unroll
        for (int nj = 0; nj < 8; ++nj) {
            half8 b = *(const half8*)(w2w + nj * 16 * 1024 + k0);
            acc[0][nj] = __builtin_amdgcn_mfma_f32_16x16x32_f16(a0, b, acc[0][nj], 0, 0, 0);
            acc[1][nj] = __builtin_amdgcn_mfma_f32_16x16x32_f16(a1, b, acc[1][nj], 0, 0, 0);
        }
    }
    // K-half 2: A from G (g), W2 k in [512,1024)
#pragma unroll 4
    for (int kt = 0; kt < 16; ++kt) {
        const int k0 = kt * 32;
        half8 a0 = *(const half8*)&G[l16][k0 + quad * 8];
        half8 a1 = *(const half8*)&G[16 + l16][k0 + quad * 8];
#pragma unroll
        for (int nj = 0; nj < 8; ++nj) {
            half8 b = *(const half8*)(w2w + nj * 16 * 1024 + 512 + k0);
            acc[0][nj] = __builtin_amdgcn_mfma_f32_16x16x32_f16(a0, b, acc[0][nj], 0, 0, 0);
            acc[1][nj] = __builtin_amdgcn_mfma_f32_16x16x32_f16(a1, b, acc[1][nj], 0, 0, 0);
        }
    }

    // ---- epilogue (base re-read from global, L3-hot)
#pragma unroll
    for (int nj = 0; nj < 8; ++nj) {
        const int col = wn + nj * 16 + l16;
        const float cv = cvec[col];
#pragma unroll
        for (int mi = 0; mi < 2; ++mi)
#pragma unroll
            for (int i = 0; i < 4; ++i) {
                const int rl = mi * 16 + quad * 4 + i;
                const long row = m0 + rl;
                float v = fmaxf(acc[mi][nj][i] + cv, 0.f)
                        + (float)base[row * F_DIM + col];
                out[row * F_DIM + col] = v;
            }
    }
}

// ---------------------------------------------------------------------------
extern "C" void kernel_launch(void* const* d_in, const int* in_sizes, int n_in,
                              void* d_out, int out_size, void* d_ws, size_t ws_size,
                              hipStream_t stream)
{
    (void)in_sizes; (void)n_in; (void)out_size; (void)ws_size;
    const float* gf  = (const float*)d_in[0];
    const float* loc = (const float*)d_in[1];
    const float* Wq  = (const float*)d_in[2];
    const float* bq  = (const float*)d_in[3];
    const float* Wk  = (const float*)d_in[4];
    // d_in[5] = bk: dropped — contributes only a k-constant to s2 (softmax-invariant)
    const float* Wv  = (const float*)d_in[6];
    const float* bv  = (const float*)d_in[7];
    const float* wdr = (const float*)d_in[8];
    const float* bdr = (const float*)d_in[9];
    const float* Wf  = (const float*)d_in[10];
    const float* bfv = (const float*)d_in[11];
    float* out = (float*)d_out;

    char* ws = (char*)d_ws;
    _Float16* W1   = (_Float16*)(ws + OFF_W1);
    _Float16* W2   = (_Float16*)(ws + OFF_W2);
    float*    c1   = (float*)(ws + OFF_C1);
    float*    cvec = (float*)(ws + OFF_CVEC);
    _Float16* base = (_Float16*)(ws + OFF_BASE);

    precompute_w<<<dim3(16, 16, 4), 256, 0, stream>>>(
        Wq, Wk, Wv, Wf, wdr, bq, bv, bdr, bfv, W1, W2, c1, cvec);
    fused_all<<<512, 256, 0, stream>>>(
        gf, loc, W1, W2, c1, cvec, wdr, bdr, base, out);
}